// Round 1
// baseline (2041.657 us; speedup 1.0000x reference)
//
#include <hip/hip_runtime.h>
#include <hip/hip_bf16.h>
#include <cstdint>
#include <cstddef>

// Problem constants (match reference)
#define Hdim 1024
#define Vdim 32000
#define LAYERS 3
#define Bdim 64
#define Tdim 32
#define BT 2048      // B*T
#define G3H 3072     // 3*H

using bf16 = __bf16;
using bf16x8 = __attribute__((ext_vector_type(8))) __bf16;  // one MFMA A/B fragment (4 VGPRs)
using bf16x4 = __attribute__((ext_vector_type(4))) __bf16;
using f32x4  = __attribute__((ext_vector_type(4))) float;

// ---------------- fp32 -> bf16 conversion (weights) ----------------
__global__ __launch_bounds__(256) void cvt_f32_bf16(const float* __restrict__ src,
                                                    bf16* __restrict__ dst, int n4) {
  int i = blockIdx.x * 256 + threadIdx.x;
  if (i < n4) {
    f32x4 v = ((const f32x4*)src)[i];
    bf16x4 o;
    o[0] = (bf16)v[0]; o[1] = (bf16)v[1]; o[2] = (bf16)v[2]; o[3] = (bf16)v[3];
    ((bf16x4*)dst)[i] = o;
  }
}

// ---------------- embedding + relu -> bf16 x0 ----------------
// row = b*T + t ; ids[b,0]=0 (SOS), ids[b,t]=target[b,t-1]
__global__ __launch_bounds__(256) void embed_relu(const int* __restrict__ tgt,
                                                  const float* __restrict__ emb,
                                                  bf16* __restrict__ x) {
  int row = blockIdx.x;
  int b = row >> 5, t = row & 31;
  int id = (t == 0) ? 0 : tgt[b * Tdim + t - 1];
  const f32x4* src = (const f32x4*)(emb + (size_t)id * Hdim);
  bf16x4* dst = (bf16x4*)(x + (size_t)row * Hdim);
  f32x4 v = src[threadIdx.x];
  bf16x4 o;
  o[0] = (bf16)fmaxf(v[0], 0.f); o[1] = (bf16)fmaxf(v[1], 0.f);
  o[2] = (bf16)fmaxf(v[2], 0.f); o[3] = (bf16)fmaxf(v[3], 0.f);
  dst[threadIdx.x] = o;
}

// ---------------- hidden-state init from encoder_hidden[l] ----------------
__global__ __launch_bounds__(256) void hinit(const float* __restrict__ eh,
                                             float* __restrict__ h32,
                                             bf16* __restrict__ hbf) {
  int i = blockIdx.x * 256 + threadIdx.x;   // i indexes groups of 4; 64 blocks * 256 * 4 = 65536
  f32x4 v = ((const f32x4*)eh)[i];
  ((f32x4*)h32)[i] = v;
  bf16x4 o;
  o[0] = (bf16)v[0]; o[1] = (bf16)v[1]; o[2] = (bf16)v[2]; o[3] = (bf16)v[3];
  ((bf16x4*)hbf)[i] = o;
}

// ---------------- C = A @ B^T (+bias), bf16 inputs, fp32 out ----------------
// A: [M,K] row-major bf16. Bm: [N,K] row-major bf16 (i.e. weights W[n,k]).
// Block = 4 waves, block tile 128x128, wave tile 64x64 (4x4 of 16x16x32 MFMA).
// Direct global fragment loads (no LDS) — correctness-first baseline.
// MFMA layouts (HW-verified, guide §3): A[m=lane&15][k=quad*8+j];
// B-op provides B[k][n] with n=lane&15, k=quad*8+j -> load W[n][k] contiguous;
// C/D: col=lane&15, row=quad*4+reg.
template <bool BIAS>
__global__ __launch_bounds__(256) void gemm_xwt(const bf16* __restrict__ A,
                                                const bf16* __restrict__ Bm,
                                                const float* __restrict__ bias,
                                                float* __restrict__ C,
                                                int M, int N, int K) {
  int wave = threadIdx.x >> 6, lane = threadIdx.x & 63;
  int wr = wave >> 1, wc = wave & 1;
  int lane15 = lane & 15, quad = lane >> 4;
  int m0 = blockIdx.y * 128 + wr * 64;
  int n0 = blockIdx.x * 128 + wc * 64;
  const bf16* Ap = A + (size_t)(m0 + lane15) * K + quad * 8;
  const bf16* Bp = Bm + (size_t)(n0 + lane15) * K + quad * 8;

  f32x4 acc[4][4] = {};
  for (int k0 = 0; k0 < K; k0 += 32) {
    bf16x8 a[4], b[4];
#pragma unroll
    for (int mi = 0; mi < 4; mi++) a[mi] = *(const bf16x8*)(Ap + (size_t)mi * 16 * K + k0);
#pragma unroll
    for (int ni = 0; ni < 4; ni++) b[ni] = *(const bf16x8*)(Bp + (size_t)ni * 16 * K + k0);
#pragma unroll
    for (int mi = 0; mi < 4; mi++)
#pragma unroll
      for (int ni = 0; ni < 4; ni++)
        acc[mi][ni] = __builtin_amdgcn_mfma_f32_16x16x32_bf16(a[mi], b[ni], acc[mi][ni], 0, 0, 0);
  }
#pragma unroll
  for (int mi = 0; mi < 4; mi++)
#pragma unroll
    for (int ni = 0; ni < 4; ni++) {
      int col = n0 + ni * 16 + lane15;
      float bv = BIAS ? bias[col] : 0.f;
#pragma unroll
      for (int r = 0; r < 4; r++) {
        int row = m0 + mi * 16 + quad * 4 + r;
        C[(size_t)row * N + col] = acc[mi][ni][r] + bv;
      }
    }
}

// ---------------- one GRU time step, fused: hp = h@Whh^T + bhh; gates; h update ----
// One wave per block; block computes a 16(b) x 16(i) patch for all 3 gates.
// Reads prev-step h buffers, writes next-step buffers (ping-pong -> no WAR race).
__global__ __launch_bounds__(64) void gru_step(const bf16* __restrict__ hbf_p,
                                               const float* __restrict__ h32_p,
                                               const bf16* __restrict__ Whh,   // [3H,H] bf16
                                               const float* __restrict__ bhh,  // [3H]
                                               const float* __restrict__ xp,   // [BT,3H]
                                               float* __restrict__ h32_n,
                                               bf16* __restrict__ hbf_n,
                                               bf16* __restrict__ y,           // [BT,H] bf16
                                               float* __restrict__ finals,     // d_out tail for this layer
                                               int t) {
  int lane = threadIdx.x & 63;
  int lane15 = lane & 15, quad = lane >> 4;
  int i0 = blockIdx.x * 16, b0 = blockIdx.y * 16;
  const bf16* Ap = hbf_p + (size_t)(b0 + lane15) * Hdim + quad * 8;
  const bf16* Br = Whh + (size_t)(0 * Hdim + i0 + lane15) * Hdim + quad * 8;
  const bf16* Bz = Whh + (size_t)(1 * Hdim + i0 + lane15) * Hdim + quad * 8;
  const bf16* Bn = Whh + (size_t)(2 * Hdim + i0 + lane15) * Hdim + quad * 8;

  f32x4 ar = {}, az = {}, an = {};
  for (int k0 = 0; k0 < Hdim; k0 += 32) {
    bf16x8 a  = *(const bf16x8*)(Ap + k0);
    bf16x8 br = *(const bf16x8*)(Br + k0);
    bf16x8 bz = *(const bf16x8*)(Bz + k0);
    bf16x8 bn = *(const bf16x8*)(Bn + k0);
    ar = __builtin_amdgcn_mfma_f32_16x16x32_bf16(a, br, ar, 0, 0, 0);
    az = __builtin_amdgcn_mfma_f32_16x16x32_bf16(a, bz, az, 0, 0, 0);
    an = __builtin_amdgcn_mfma_f32_16x16x32_bf16(a, bn, an, 0, 0, 0);
  }
  int i = i0 + lane15;
  float bhr = bhh[i], bhz = bhh[Hdim + i], bhn = bhh[2 * Hdim + i];
#pragma unroll
  for (int r = 0; r < 4; r++) {
    int b = b0 + quad * 4 + r;
    size_t m = (size_t)b * Tdim + t;
    float xr = xp[m * G3H + i];
    float xz = xp[m * G3H + Hdim + i];
    float xn = xp[m * G3H + 2 * Hdim + i];
    float hpr = ar[r] + bhr, hpz = az[r] + bhz, hpn = an[r] + bhn;
    float rg = 1.f / (1.f + __expf(-(xr + hpr)));
    float zg = 1.f / (1.f + __expf(-(xz + hpz)));
    float ng = tanhf(xn + rg * hpn);
    float hold = h32_p[(size_t)b * Hdim + i];
    float hnew = (1.f - zg) * ng + zg * hold;
    h32_n[(size_t)b * Hdim + i] = hnew;
    hbf_n[(size_t)b * Hdim + i] = (bf16)hnew;
    y[m * Hdim + i] = (bf16)hnew;
    if (t == Tdim - 1) finals[(size_t)b * Hdim + i] = hnew;
  }
}

// ---------------- in-place log_softmax over V per row ----------------
__global__ __launch_bounds__(256) void logsoftmax(float* __restrict__ out) {
  __shared__ float sm[256], ss[256];
  int row = blockIdx.x;
  float* x = out + (size_t)row * Vdim;
  float m = -1e30f, s = 0.f;
  for (int j = threadIdx.x; j < Vdim; j += 256) {
    float v = x[j];
    float nm = fmaxf(m, v);
    s = s * __expf(m - nm) + __expf(v - nm);
    m = nm;
  }
  sm[threadIdx.x] = m; ss[threadIdx.x] = s;
  __syncthreads();
  for (int off = 128; off; off >>= 1) {
    if (threadIdx.x < off) {
      float m1 = sm[threadIdx.x], s1 = ss[threadIdx.x];
      float m2 = sm[threadIdx.x + off], s2 = ss[threadIdx.x + off];
      float mm = fmaxf(m1, m2);
      sm[threadIdx.x] = mm;
      ss[threadIdx.x] = s1 * __expf(m1 - mm) + s2 * __expf(m2 - mm);
    }
    __syncthreads();
  }
  float lse = sm[0] + logf(ss[0]);
  for (int j = threadIdx.x; j < Vdim; j += 256) x[j] -= lse;
}

extern "C" void kernel_launch(void* const* d_in, const int* in_sizes, int n_in,
                              void* d_out, int out_size, void* d_ws, size_t ws_size,
                              hipStream_t stream) {
  // d_in order per setup_inputs: 0 enc_out(unused) 1 enc_hidden 2 target 3 emb
  //                              4 W_ih 5 W_hh 6 b_ih 7 b_hh 8 W_out 9 b_out
  const float* enc_hidden = (const float*)d_in[1];
  const int*   target     = (const int*)d_in[2];
  const float* emb        = (const float*)d_in[3];
  const float* W_ih       = (const float*)d_in[4];
  const float* W_hh       = (const float*)d_in[5];
  const float* b_ih       = (const float*)d_in[6];
  const float* b_hh       = (const float*)d_in[7];
  const float* W_out      = (const float*)d_in[8];
  const float* b_out      = (const float*)d_in[9];

  float* out = (float*)d_out;                       // [BT, V] logits/logprobs
  float* finals = out + (size_t)BT * Vdim;          // [L, B, H]

  // workspace carve-up (~137.6 MB total)
  uint8_t* wsp = (uint8_t*)d_ws;
  auto alloc = [&](size_t bytes) {
    uint8_t* p = wsp;
    wsp += (bytes + 255) & ~(size_t)255;
    return p;
  };
  bf16* wih_bf  = (bf16*)alloc((size_t)LAYERS * G3H * Hdim * 2);
  bf16* whh_bf  = (bf16*)alloc((size_t)LAYERS * G3H * Hdim * 2);
  bf16* wout_bf = (bf16*)alloc((size_t)Vdim * Hdim * 2);
  bf16* xA      = (bf16*)alloc((size_t)BT * Hdim * 2);
  bf16* xB      = (bf16*)alloc((size_t)BT * Hdim * 2);
  float* xp     = (float*)alloc((size_t)BT * G3H * 4);
  float* h32a   = (float*)alloc((size_t)Bdim * Hdim * 4);
  float* h32b   = (float*)alloc((size_t)Bdim * Hdim * 4);
  bf16* hbfa    = (bf16*)alloc((size_t)Bdim * Hdim * 2);
  bf16* hbfb    = (bf16*)alloc((size_t)Bdim * Hdim * 2);
  float* h32[2] = {h32a, h32b};
  bf16*  hbf[2] = {hbfa, hbfb};

  // weight conversions (every call — ws is re-poisoned by the harness)
  {
    int n4 = LAYERS * G3H * Hdim / 4;  // 2,359,296
    cvt_f32_bf16<<<(n4 + 255) / 256, 256, 0, stream>>>(W_ih, wih_bf, n4);
    cvt_f32_bf16<<<(n4 + 255) / 256, 256, 0, stream>>>(W_hh, whh_bf, n4);
    int m4 = Vdim * Hdim / 4;          // 8,192,000
    cvt_f32_bf16<<<(m4 + 255) / 256, 256, 0, stream>>>(W_out, wout_bf, m4);
  }

  embed_relu<<<BT, 256, 0, stream>>>(target, emb, xA);

  bf16* xin = xA;
  bf16* xout_ = xB;
  for (int l = 0; l < LAYERS; l++) {
    hinit<<<64, 256, 0, stream>>>(enc_hidden + (size_t)l * Bdim * Hdim, h32[0], hbf[0]);
    // xp = x @ W_ih[l]^T + b_ih[l]  : M=2048, N=3072, K=1024
    dim3 g1(G3H / 128, BT / 128);
    gemm_xwt<true><<<g1, 256, 0, stream>>>(xin, wih_bf + (size_t)l * G3H * Hdim,
                                           b_ih + (size_t)l * G3H, xp, BT, G3H, Hdim);
    for (int t = 0; t < Tdim; t++) {
      int p = t & 1;
      gru_step<<<dim3(Hdim / 16, Bdim / 16), 64, 0, stream>>>(
          hbf[p], h32[p], whh_bf + (size_t)l * G3H * Hdim, b_hh + (size_t)l * G3H,
          xp, h32[p ^ 1], hbf[p ^ 1], xout_, finals + (size_t)l * Bdim * Hdim, t);
    }
    bf16* tmp = xin; xin = xout_; xout_ = tmp;
  }

  // logits = x @ W_out^T + b_out : M=2048, N=32000, K=1024 -> d_out
  dim3 g2(Vdim / 128, BT / 128);
  gemm_xwt<true><<<g2, 256, 0, stream>>>(xin, wout_bf, b_out, out, BT, Vdim, Hdim);

  logsoftmax<<<BT, 256, 0, stream>>>(out);
}